// Round 1
// baseline (1244.553 us; speedup 1.0000x reference)
//
#include <hip/hip_runtime.h>
#include <math.h>

// Problem constants
#define Bq 64
#define Tt 2048
#define TQn 2
#define HIDn 1024
#define ENCn 512
#define Un 256
#define FILTn 32
#define KKn 31

// Main-pass tiling
#define TTILE 128
#define NCHUNK (Tt / TTILE)   // 16
#define RROWS 16
#define NGROUP (TTILE / RROWS) // 8

// ---------------- precompute kernels (all tiny) ----------------

// g[b,u] = pq[b,u] + bm[u] + bl[u] + (conv_b @ Wl)[u]
__global__ void k_g(const float* __restrict__ query, const float* __restrict__ Wq,
                    const float* __restrict__ bq, const float* __restrict__ bm,
                    const float* __restrict__ bl, const float* __restrict__ Wl,
                    const float* __restrict__ conv_b, float* __restrict__ g)
{
    const int b = blockIdx.x, u = threadIdx.x;
    const float* q = query + ((size_t)b * TQn + 1) * HIDn;  // query[:,1,:]
    float acc = bq[u];
    for (int h = 0; h < HIDn; ++h) acc += q[h] * Wq[h * Un + u];
    float cb = 0.f;
    for (int f = 0; f < FILTn; ++f) cb += conv_b[f] * Wl[f * Un + u];
    g[b * Un + u] = acc + bm[u] + bl[u] + cb;
}

// WlWe[f,v] = sum_u Wl[f,u] * We[u,v]
__global__ void k_wlwe(const float* __restrict__ Wl, const float* __restrict__ We,
                       float* __restrict__ WlWe)
{
    const int f = blockIdx.x, v = threadIdx.x;
    float acc = 0.f;
    for (int u = 0; u < Un; ++u) acc += Wl[f * Un + u] * We[u * Un + v];
    WlWe[f * Un + v] = acc;
}

// WmWe[e,v] = sum_u Wm[e,u] * We[u,v]
__global__ void k_wmwe(const float* __restrict__ Wm, const float* __restrict__ We,
                       float* __restrict__ WmWe)
{
    const int e = blockIdx.x, v = threadIdx.x;
    float acc = 0.f;
    for (int u = 0; u < Un; ++u) acc += Wm[e * Un + u] * We[u * Un + v];
    WmWe[e * Un + v] = acc;
}

// CW[k,v] = sum_f conv_w[f,0,k] * WlWe[f,v]
__global__ void k_cw(const float* __restrict__ conv_w, const float* __restrict__ WlWe,
                     float* __restrict__ CW)
{
    const int k = blockIdx.x, v = threadIdx.x;
    float acc = 0.f;
    for (int f = 0; f < FILTn; ++f) acc += conv_w[f * KKn + k] * WlWe[f * Un + v];
    CW[k * Un + v] = acc;
}

// zconst[b,v] = be[v] + sum_u g[b,u] * We[u,v]
__global__ void k_zconst(const float* __restrict__ g, const float* __restrict__ We,
                         const float* __restrict__ be, float* __restrict__ zconst)
{
    const int b = blockIdx.x, v = threadIdx.x;
    float acc = be[v];
    for (int u = 0; u < Un; ++u) acc += g[b * Un + u] * We[u * Un + v];
    zconst[b * Un + v] = acc;
}

// ---------------- main fused pass ----------------
// Per block: b, t-chunk of 128 rows. 128 threads, each owns v columns {tid, tid+128}.
// z[t,v] = memory[t,:]·WmWe[:,v] + sum_k state[t-15+k]·CW[k,v] + zconst[b,v]
// energy[t] = v_a · tanh(z[t,:]);  s = sigmoid(energy)
// partials: A[e] = sum_t state[t]·mem[t,e];  S[e] = sum_t s[t]·mem[t,e];
//           ssum = sum_t s[t];  stsum = sum_t state[t]
__global__ __launch_bounds__(128) void attn_main(
    const float* __restrict__ memory, const float* __restrict__ state,
    const float* __restrict__ WmWe, const float* __restrict__ CW,
    const float* __restrict__ zconst, const float* __restrict__ v_a,
    float* __restrict__ pA, float* __restrict__ pS,
    float* __restrict__ pSsum, float* __restrict__ pStsum)
{
    const int blk = blockIdx.x;
    const int b = blk >> 4;          // / NCHUNK
    const int c = blk & (NCHUNK - 1);
    const int t0 = c * TTILE;
    const int tid = threadIdx.x;

    __shared__ __align__(16) float mem_s[RROWS * ENCn];  // 32 KB
    __shared__ float state_s[TTILE + 30];
    __shared__ float ewave_s[2][RROWS];
    __shared__ float s_s[RROWS];
    __shared__ float red_s[2];

    // state window [t0-15, t0+TTILE+15), zero-padded at sequence ends only
    for (int i = tid; i < TTILE + 30; i += 128) {
        const int t = t0 - 15 + i;
        state_s[i] = (t >= 0 && t < Tt) ? state[b * Tt + t] : 0.0f;
    }

    const int v0 = tid, v1 = tid + 128;
    const float va0 = v_a[v0], va1 = v_a[v1];
    const float zc0 = zconst[b * Un + v0], zc1 = zconst[b * Un + v1];
    float cw0[KKn], cw1[KKn];
    #pragma unroll
    for (int k = 0; k < KKn; ++k) {
        cw0[k] = CW[k * Un + v0];
        cw1[k] = CW[k * Un + v1];
    }

    float accA[4] = {0.f, 0.f, 0.f, 0.f};
    float accS[4] = {0.f, 0.f, 0.f, 0.f};
    float ssum = 0.f;

    const float4* __restrict__ memv =
        (const float4*)(memory + ((size_t)b * Tt + t0) * ENCn);

    for (int g = 0; g < NGROUP; ++g) {
        __syncthreads();  // protect mem_s / ewave_s reuse from previous group
        // stage 16 rows (16*512 floats = 2048 float4), 16 per thread
        for (int idx = tid; idx < RROWS * ENCn / 4; idx += 128)
            ((float4*)mem_s)[idx] = memv[(size_t)g * (RROWS * ENCn / 4) + idx];
        __syncthreads();

        // GEMM: 16 rows x 2 cols per thread over K=512
        float acc0[RROWS], acc1[RROWS];
        #pragma unroll
        for (int r = 0; r < RROWS; ++r) { acc0[r] = 0.f; acc1[r] = 0.f; }

        #pragma unroll 2
        for (int e = 0; e < ENCn; e += 4) {
            const float w00 = WmWe[(e + 0) * Un + v0];
            const float w01 = WmWe[(e + 1) * Un + v0];
            const float w02 = WmWe[(e + 2) * Un + v0];
            const float w03 = WmWe[(e + 3) * Un + v0];
            const float w10 = WmWe[(e + 0) * Un + v1];
            const float w11 = WmWe[(e + 1) * Un + v1];
            const float w12 = WmWe[(e + 2) * Un + v1];
            const float w13 = WmWe[(e + 3) * Un + v1];
            #pragma unroll
            for (int r = 0; r < RROWS; ++r) {
                const float4 m = *(const float4*)&mem_s[r * ENCn + e];  // wave-broadcast
                acc0[r] += m.x * w00; acc0[r] += m.y * w01;
                acc0[r] += m.z * w02; acc0[r] += m.w * w03;
                acc1[r] += m.x * w10; acc1[r] += m.y * w11;
                acc1[r] += m.z * w12; acc1[r] += m.w * w13;
            }
        }

        // conv + tanh + energy partial, reduce 128 threads -> s per row
        #pragma unroll
        for (int r = 0; r < RROWS; ++r) {
            const int i = g * RROWS + r;  // local row; state_s[i] == state[t0+i-15]
            float conv0 = 0.f, conv1 = 0.f;
            #pragma unroll
            for (int k = 0; k < KKn; ++k) {
                const float sv = state_s[i + k];
                conv0 += sv * cw0[k];
                conv1 += sv * cw1[k];
            }
            const float h0 = tanhf(acc0[r] + conv0 + zc0);
            const float h1 = tanhf(acc1[r] + conv1 + zc1);
            float ep = h0 * va0 + h1 * va1;
            #pragma unroll
            for (int off = 32; off >= 1; off >>= 1) ep += __shfl_xor(ep, off, 64);
            if ((tid & 63) == 0) ewave_s[tid >> 6][r] = ep;
        }
        __syncthreads();
        if (tid < RROWS) {
            const float energy = ewave_s[0][tid] + ewave_s[1][tid];
            const float s = 1.0f / (1.0f + expf(-energy));
            s_s[tid] = s;
            ssum += s;
        }
        __syncthreads();

        // weighted accumulation: thread owns e = 4*tid .. 4*tid+3
        #pragma unroll
        for (int r = 0; r < RROWS; ++r) {
            const float st = state_s[15 + g * RROWS + r];
            const float sv = s_s[r];
            const float4 m = *(const float4*)&mem_s[r * ENCn + (tid << 2)];
            accA[0] += st * m.x; accA[1] += st * m.y;
            accA[2] += st * m.z; accA[3] += st * m.w;
            accS[0] += sv * m.x; accS[1] += sv * m.y;
            accS[2] += sv * m.z; accS[3] += sv * m.w;
        }
    }

    __syncthreads();
    // write per-chunk partials
    ((float4*)(pA + (size_t)blk * ENCn))[tid] = make_float4(accA[0], accA[1], accA[2], accA[3]);
    ((float4*)(pS + (size_t)blk * ENCn))[tid] = make_float4(accS[0], accS[1], accS[2], accS[3]);

    if (tid < RROWS) s_s[tid] = ssum;
    float st = state_s[15 + tid];  // TTILE == 128 == blockDim
    #pragma unroll
    for (int off = 32; off >= 1; off >>= 1) st += __shfl_xor(st, off, 64);
    if ((tid & 63) == 0) red_s[tid >> 6] = st;
    __syncthreads();
    if (tid == 0) {
        float ss = 0.f;
        #pragma unroll
        for (int r = 0; r < RROWS; ++r) ss += s_s[r];
        pSsum[blk] = ss;
        pStsum[blk] = red_s[0] + red_s[1];
    }
}

// ---------------- finalize ----------------
// context[b,u] = (A[b,:] + S[b,:]/Σs) @ Wm[:,u] + bm[u]*(Σstate + 1)
__global__ void k_final(const float* __restrict__ pA, const float* __restrict__ pS,
                        const float* __restrict__ pSsum, const float* __restrict__ pStsum,
                        const float* __restrict__ Wm, const float* __restrict__ bm,
                        float* __restrict__ out)
{
    const int b = blockIdx.x, tid = threadIdx.x;
    __shared__ float ctx[ENCn];
    __shared__ float sums[2];
    if (tid == 0) {
        float ss = 0.f, ts = 0.f;
        for (int c = 0; c < NCHUNK; ++c) {
            ss += pSsum[b * NCHUNK + c];
            ts += pStsum[b * NCHUNK + c];
        }
        sums[0] = ss; sums[1] = ts;
    }
    __syncthreads();
    const float inv = 1.0f / sums[0];
    const float tplus = sums[1] + 1.0f;  // sum of alignment == 1 exactly
    for (int e = tid; e < ENCn; e += Un) {
        float a = 0.f, s = 0.f;
        for (int c = 0; c < NCHUNK; ++c) {
            a += pA[((size_t)(b * NCHUNK + c)) * ENCn + e];
            s += pS[((size_t)(b * NCHUNK + c)) * ENCn + e];
        }
        ctx[e] = a + s * inv;
    }
    __syncthreads();
    float acc = 0.f;
    for (int e = 0; e < ENCn; ++e) acc += ctx[e] * Wm[e * Un + tid];
    out[b * Un + tid] = acc + bm[tid] * tplus;
}

// ---------------- launch ----------------
extern "C" void kernel_launch(void* const* d_in, const int* in_sizes, int n_in,
                              void* d_out, int out_size, void* d_ws, size_t ws_size,
                              hipStream_t stream)
{
    const float* query  = (const float*)d_in[0];
    const float* state  = (const float*)d_in[1];
    const float* memory = (const float*)d_in[2];
    const float* Wq     = (const float*)d_in[3];
    const float* bq     = (const float*)d_in[4];
    const float* Wm     = (const float*)d_in[5];
    const float* bm     = (const float*)d_in[6];
    const float* Wl     = (const float*)d_in[7];
    const float* bl     = (const float*)d_in[8];
    const float* conv_w = (const float*)d_in[9];
    const float* conv_b = (const float*)d_in[10];
    const float* We     = (const float*)d_in[11];
    const float* be     = (const float*)d_in[12];
    const float* v_a    = (const float*)d_in[13];
    float* out = (float*)d_out;

    // workspace layout (floats); total 1,230,592 floats ≈ 4.93 MB
    float* ws      = (float*)d_ws;
    float* g_      = ws;                 // 64*256   = 16384
    float* WlWe    = ws + 16384;         // 32*256   = 8192
    float* WmWe    = ws + 24576;         // 512*256  = 131072
    float* CW      = ws + 155648;        // 31*256   = 7936 (+pad)
    float* zconst  = ws + 163584;        // 64*256   = 16384
    float* pA      = ws + 179968;        // 1024*512 = 524288
    float* pS      = ws + 704256;        // 1024*512 = 524288
    float* pSsum   = ws + 1228544;       // 1024
    float* pStsum  = ws + 1229568;       // 1024

    hipLaunchKernelGGL(k_wlwe,   dim3(FILTn), dim3(Un), 0, stream, Wl, We, WlWe);
    hipLaunchKernelGGL(k_wmwe,   dim3(ENCn),  dim3(Un), 0, stream, Wm, We, WmWe);
    hipLaunchKernelGGL(k_g,      dim3(Bq),    dim3(Un), 0, stream, query, Wq, bq, bm, bl, Wl, conv_b, g_);
    hipLaunchKernelGGL(k_cw,     dim3(KKn),   dim3(Un), 0, stream, conv_w, WlWe, CW);
    hipLaunchKernelGGL(k_zconst, dim3(Bq),    dim3(Un), 0, stream, g_, We, be, zconst);
    hipLaunchKernelGGL(attn_main, dim3(Bq * NCHUNK), dim3(128), 0, stream,
                       memory, state, WmWe, CW, zconst, v_a, pA, pS, pSsum, pStsum);
    hipLaunchKernelGGL(k_final,  dim3(Bq),    dim3(Un), 0, stream, pA, pS, pSsum, pStsum, Wm, bm, out);
}

// Round 2
// 561.796 us; speedup vs baseline: 2.2153x; 2.2153x over previous
//
#include <hip/hip_runtime.h>
#include <math.h>

// Problem constants
#define Bq 64
#define Tt 2048
#define TQn 2
#define HIDn 1024
#define ENCn 512
#define Un 256
#define FILTn 32
#define KKn 31

// Main-pass tiling
#define TTILE 32
#define NCHUNK (Tt / TTILE)     // 64
#define LDK 520                 // padded LDS row length in bf16 (512 + 8) -> 16B-aligned rows, bank-balanced

typedef short short8 __attribute__((ext_vector_type(8)));
typedef float f32x4  __attribute__((ext_vector_type(4)));
typedef unsigned short ushort_t;
typedef unsigned int   uint_t;

__device__ __forceinline__ ushort_t f2b(float f) {
    union { float f; uint_t u; } x; x.f = f;
    uint_t r = x.u + 0x7fffu + ((x.u >> 16) & 1u);   // RNE
    return (ushort_t)(r >> 16);
}
__device__ __forceinline__ float b2f(ushort_t u) {
    union { uint_t i; float f; } x; x.i = ((uint_t)u) << 16;
    return x.f;
}

// ---------------- precompute kernels ----------------

// WlWe[f,v] = sum_u Wl[f,u] * We[u,v]   (fp32, 32x256)
__global__ void k_wlwe(const float* __restrict__ Wl, const float* __restrict__ We,
                       float* __restrict__ WlWe)
{
    const int f = blockIdx.x, v = threadIdx.x;
    float acc = 0.f;
    #pragma unroll 8
    for (int u = 0; u < Un; ++u) acc += Wl[f * Un + u] * We[u * Un + v];
    WlWe[f * Un + v] = acc;
}

// WmWeT[v,e] = bf16( sum_u Wm[e,u] * We[u,v] )   (bf16, 256x512, k(e)-contiguous)
__global__ void k_wmwet(const float* __restrict__ Wm, const float* __restrict__ We,
                        ushort_t* __restrict__ WmWeT)
{
    const int e = blockIdx.x, v = threadIdx.x;
    float acc = 0.f;
    #pragma unroll 8
    for (int u = 0; u < Un; ++u) acc += Wm[(size_t)e * Un + u] * We[(size_t)u * Un + v];
    WmWeT[(size_t)v * ENCn + e] = f2b(acc);
}

// CWT[v,k] = bf16( sum_f conv_w[f,0,k] * WlWe[f,v] ), k=31 zero pad  (bf16, 256x32)
__global__ void k_cwt(const float* __restrict__ conv_w, const float* __restrict__ WlWe,
                      ushort_t* __restrict__ CWT)
{
    const int k = blockIdx.x, v = threadIdx.x;   // k in [0,32)
    float acc = 0.f;
    if (k < KKn) {
        #pragma unroll
        for (int f = 0; f < FILTn; ++f) acc += conv_w[f * KKn + k] * WlWe[f * Un + v];
    }
    CWT[(size_t)v * 32 + k] = f2b(acc);
}

// g[b,u] += partial of (q1 @ Wq); y==0 adds bq+bm+bl+conv_b@Wl.  grid (64,8)
__global__ void k_g(const float* __restrict__ query, const float* __restrict__ Wq,
                    const float* __restrict__ bq, const float* __restrict__ bm,
                    const float* __restrict__ bl, const float* __restrict__ Wl,
                    const float* __restrict__ conv_b, float* __restrict__ g)
{
    const int b = blockIdx.x, hs = blockIdx.y * 128, u = threadIdx.x;
    const float* q = query + ((size_t)b * TQn + 1) * HIDn + hs;
    float acc = 0.f;
    #pragma unroll 8
    for (int h = 0; h < 128; ++h) acc += q[h] * Wq[(size_t)(hs + h) * Un + u];
    if (blockIdx.y == 0) {
        acc += bq[u] + bm[u] + bl[u];
        #pragma unroll
        for (int f = 0; f < FILTn; ++f) acc += conv_b[f] * Wl[f * Un + u];
    }
    atomicAdd(&g[b * Un + u], acc);
}

// zconst[b,v] += partial of (g @ We); y==0 adds be.  grid (64,4)
__global__ void k_zconst(const float* __restrict__ g, const float* __restrict__ We,
                         const float* __restrict__ be, float* __restrict__ zconst)
{
    const int b = blockIdx.x, us = blockIdx.y * 64, v = threadIdx.x;
    float acc = 0.f;
    #pragma unroll 8
    for (int u = us; u < us + 64; ++u) acc += g[b * Un + u] * We[(size_t)u * Un + v];
    if (blockIdx.y == 0) acc += be[v];
    atomicAdd(&zconst[b * Un + v], acc);
}

// ---------------- main fused MFMA pass ----------------
// Block: (b, 32-row t-chunk), 256 threads = 4 waves (wave w owns cols w*64..w*64+63).
// z = mem_bf16 @ WmWeT^T (K=512, 16 MFMA steps) + statewin @ CWT^T (K=32, 1 step) + zconst
// energy -> sigmoid -> s; partial A/S accumulated via atomics.
__global__ __launch_bounds__(256) void attn_main(
    const float* __restrict__ memory, const float* __restrict__ state,
    const ushort_t* __restrict__ WmWeT, const ushort_t* __restrict__ CWT,
    const float* __restrict__ zconst, const float* __restrict__ v_a,
    float* __restrict__ zA, float* __restrict__ zS,
    float* __restrict__ zSsum, float* __restrict__ zStsum)
{
    const int blk = blockIdx.x;
    const int b  = blk >> 6;            // / NCHUNK
    const int c  = blk & (NCHUNK - 1);
    const int t0 = c * TTILE;
    const int tid = threadIdx.x;

    __shared__ __align__(16) ushort_t mem_s[TTILE * LDK];   // 33280 B
    __shared__ __align__(16) float sw_raw[80];
    __shared__ __align__(16) float ep_s[4][TTILE];
    __shared__ __align__(16) float s_s[TTILE];
    float* sw = sw_raw + 1;   // sw[i] = state[t0-15+i]; sw[15+4k] is 16B-aligned

    // state window [t0-15, t0+47], zero-padded at sequence ends
    for (int i = tid; i < TTILE + 31; i += 256) {
        const int t = t0 - 15 + i;
        sw[i] = (t >= 0 && t < Tt) ? state[b * Tt + t] : 0.0f;
    }

    // stage 32x512 fp32 -> bf16 LDS tile (row-major, padded rows)
    const float4* memv4 = (const float4*)(memory + ((size_t)b * Tt + t0) * ENCn);
    #pragma unroll
    for (int i = 0; i < 8; ++i) {
        const int idx = i * 256 + tid;          // 8-float chunk id, 0..2047
        const int row = idx >> 6;               // 64 chunks per row
        const int cw8 = (idx & 63) << 3;
        const float4 m0 = memv4[2 * idx];
        const float4 m1 = memv4[2 * idx + 1];
        short8 v;
        v[0] = (short)f2b(m0.x); v[1] = (short)f2b(m0.y);
        v[2] = (short)f2b(m0.z); v[3] = (short)f2b(m0.w);
        v[4] = (short)f2b(m1.x); v[5] = (short)f2b(m1.y);
        v[6] = (short)f2b(m1.z); v[7] = (short)f2b(m1.w);
        *(short8*)&mem_s[row * LDK + cw8] = v;
    }

    const int lane = tid & 63;
    const int w    = tid >> 6;
    const int lm   = lane & 15;      // MFMA m/n index within frag
    const int lq   = lane >> 4;      // quad
    const int ncol0 = w * 64 + lm;

    const ushort_t* bp0 = WmWeT + (size_t)(ncol0 +  0) * ENCn + lq * 8;
    const ushort_t* bp1 = WmWeT + (size_t)(ncol0 + 16) * ENCn + lq * 8;
    const ushort_t* bp2 = WmWeT + (size_t)(ncol0 + 32) * ENCn + lq * 8;
    const ushort_t* bp3 = WmWeT + (size_t)(ncol0 + 48) * ENCn + lq * 8;

    f32x4 acc[2][4] = {};

    // prefetch B frags for K-step 0
    short8 bn0 = *(const short8*)bp0;
    short8 bn1 = *(const short8*)bp1;
    short8 bn2 = *(const short8*)bp2;
    short8 bn3 = *(const short8*)bp3;

    __syncthreads();

    const ushort_t* arow0 = &mem_s[(lm) * LDK + lq * 8];
    const ushort_t* arow1 = &mem_s[(16 + lm) * LDK + lq * 8];

    #pragma unroll 4
    for (int s = 0; s < 16; ++s) {
        const short8 b0 = bn0, b1 = bn1, b2 = bn2, b3 = bn3;
        const int sn = (s + 1) & 15;    // s=15 redundantly reloads step 0 (branch-free)
        bn0 = *(const short8*)(bp0 + sn * 32);
        bn1 = *(const short8*)(bp1 + sn * 32);
        bn2 = *(const short8*)(bp2 + sn * 32);
        bn3 = *(const short8*)(bp3 + sn * 32);
        const short8 a0 = *(const short8*)(arow0 + s * 32);
        const short8 a1 = *(const short8*)(arow1 + s * 32);
        acc[0][0] = __builtin_amdgcn_mfma_f32_16x16x32_bf16(a0, b0, acc[0][0], 0, 0, 0);
        acc[0][1] = __builtin_amdgcn_mfma_f32_16x16x32_bf16(a0, b1, acc[0][1], 0, 0, 0);
        acc[0][2] = __builtin_amdgcn_mfma_f32_16x16x32_bf16(a0, b2, acc[0][2], 0, 0, 0);
        acc[0][3] = __builtin_amdgcn_mfma_f32_16x16x32_bf16(a0, b3, acc[0][3], 0, 0, 0);
        acc[1][0] = __builtin_amdgcn_mfma_f32_16x16x32_bf16(a1, b0, acc[1][0], 0, 0, 0);
        acc[1][1] = __builtin_amdgcn_mfma_f32_16x16x32_bf16(a1, b1, acc[1][1], 0, 0, 0);
        acc[1][2] = __builtin_amdgcn_mfma_f32_16x16x32_bf16(a1, b2, acc[1][2], 0, 0, 0);
        acc[1][3] = __builtin_amdgcn_mfma_f32_16x16x32_bf16(a1, b3, acc[1][3], 0, 0, 0);
    }

    // conv as one extra K=32 MFMA step: A = state window taps, B = CWT
    short8 ca0, ca1;
    #pragma unroll
    for (int j = 0; j < 8; ++j) {
        ca0[j] = (short)f2b(sw[lm + lq * 8 + j]);
        ca1[j] = (short)f2b(sw[16 + lm + lq * 8 + j]);
    }
    const ushort_t* cp = CWT + (size_t)ncol0 * 32 + lq * 8;
    const short8 cb0 = *(const short8*)(cp);
    const short8 cb1 = *(const short8*)(cp + 16 * 32);
    const short8 cb2 = *(const short8*)(cp + 32 * 32);
    const short8 cb3 = *(const short8*)(cp + 48 * 32);
    acc[0][0] = __builtin_amdgcn_mfma_f32_16x16x32_bf16(ca0, cb0, acc[0][0], 0, 0, 0);
    acc[0][1] = __builtin_amdgcn_mfma_f32_16x16x32_bf16(ca0, cb1, acc[0][1], 0, 0, 0);
    acc[0][2] = __builtin_amdgcn_mfma_f32_16x16x32_bf16(ca0, cb2, acc[0][2], 0, 0, 0);
    acc[0][3] = __builtin_amdgcn_mfma_f32_16x16x32_bf16(ca0, cb3, acc[0][3], 0, 0, 0);
    acc[1][0] = __builtin_amdgcn_mfma_f32_16x16x32_bf16(ca1, cb0, acc[1][0], 0, 0, 0);
    acc[1][1] = __builtin_amdgcn_mfma_f32_16x16x32_bf16(ca1, cb1, acc[1][1], 0, 0, 0);
    acc[1][2] = __builtin_amdgcn_mfma_f32_16x16x32_bf16(ca1, cb2, acc[1][2], 0, 0, 0);
    acc[1][3] = __builtin_amdgcn_mfma_f32_16x16x32_bf16(ca1, cb3, acc[1][3], 0, 0, 0);

    // epilogue: zconst + tanh + v_a dot, reduce 16 lanes -> per-row partial energy
    float zc[4], va[4];
    #pragma unroll
    for (int nbi = 0; nbi < 4; ++nbi) {
        const int col = ncol0 + nbi * 16;
        zc[nbi] = zconst[b * Un + col];
        va[nbi] = v_a[col];
    }
    #pragma unroll
    for (int mb = 0; mb < 2; ++mb) {
        #pragma unroll
        for (int r = 0; r < 4; ++r) {
            float ep = 0.f;
            #pragma unroll
            for (int nbi = 0; nbi < 4; ++nbi) {
                const float h = tanhf(acc[mb][nbi][r] + zc[nbi]);
                ep += h * va[nbi];
            }
            ep += __shfl_xor(ep, 1, 64);
            ep += __shfl_xor(ep, 2, 64);
            ep += __shfl_xor(ep, 4, 64);
            ep += __shfl_xor(ep, 8, 64);
            if (lm == 0) ep_s[w][mb * 16 + lq * 4 + r] = ep;   // C/D: row = quad*4+reg
        }
    }
    __syncthreads();

    if (tid < 64) {
        float s = 0.f, st = 0.f;
        if (tid < TTILE) {
            const float energy = ep_s[0][tid] + ep_s[1][tid] + ep_s[2][tid] + ep_s[3][tid];
            s = 1.0f / (1.0f + expf(-energy));
            s_s[tid] = s;
            st = sw[15 + tid];
        }
        float ssum = s, stsum = st;
        #pragma unroll
        for (int off = 32; off >= 1; off >>= 1) {
            ssum  += __shfl_xor(ssum,  off, 64);
            stsum += __shfl_xor(stsum, off, 64);
        }
        if (tid == 0) {
            atomicAdd(&zSsum[b], ssum);
            atomicAdd(&zStsum[b], stsum);
        }
    }
    __syncthreads();

    // A/S weighted accumulation: thread owns e = 2*tid, 2*tid+1
    const int e0 = tid << 1;
    float aA0 = 0.f, aA1 = 0.f, aS0 = 0.f, aS1 = 0.f;
    #pragma unroll 2
    for (int r4 = 0; r4 < TTILE / 4; ++r4) {
        const float4 sv4 = *(const float4*)&s_s[r4 * 4];
        const float4 st4 = *(const float4*)&sw[15 + r4 * 4];
        const float sv[4] = {sv4.x, sv4.y, sv4.z, sv4.w};
        const float st[4] = {st4.x, st4.y, st4.z, st4.w};
        #pragma unroll
        for (int j = 0; j < 4; ++j) {
            const int r = r4 * 4 + j;
            const float m0 = b2f(mem_s[r * LDK + e0]);
            const float m1 = b2f(mem_s[r * LDK + e0 + 1]);
            aA0 += st[j] * m0; aA1 += st[j] * m1;
            aS0 += sv[j] * m0; aS1 += sv[j] * m1;
        }
    }
    atomicAdd(&zA[b * ENCn + e0],     aA0);
    atomicAdd(&zA[b * ENCn + e0 + 1], aA1);
    atomicAdd(&zS[b * ENCn + e0],     aS0);
    atomicAdd(&zS[b * ENCn + e0 + 1], aS1);
}

// ---------------- finalize ----------------
// out[b,u] += sum_{e in chunk} (zA+zS/ssum)[b,e]*Wm[e,u]; y==0 adds bm[u]*(stsum+1)
__global__ void k_final(const float* __restrict__ zA, const float* __restrict__ zS,
                        const float* __restrict__ zSsum, const float* __restrict__ zStsum,
                        const float* __restrict__ Wm, const float* __restrict__ bm,
                        float* __restrict__ out)
{
    const int b = blockIdx.x, e0 = blockIdx.y * 128, u = threadIdx.x;
    const float inv = 1.0f / zSsum[b];
    float acc = 0.f;
    #pragma unroll 4
    for (int e = e0; e < e0 + 128; ++e) {
        const float ce = zA[b * ENCn + e] + zS[b * ENCn + e] * inv;
        acc += ce * Wm[(size_t)e * Un + u];
    }
    if (blockIdx.y == 0) acc += bm[u] * (zStsum[b] + 1.0f);
    atomicAdd(&out[b * Un + u], acc);
}

// ---------------- launch ----------------
extern "C" void kernel_launch(void* const* d_in, const int* in_sizes, int n_in,
                              void* d_out, int out_size, void* d_ws, size_t ws_size,
                              hipStream_t stream)
{
    const float* query  = (const float*)d_in[0];
    const float* state  = (const float*)d_in[1];
    const float* memory = (const float*)d_in[2];
    const float* Wq     = (const float*)d_in[3];
    const float* bq     = (const float*)d_in[4];
    const float* Wm     = (const float*)d_in[5];
    const float* bm     = (const float*)d_in[6];
    const float* Wl     = (const float*)d_in[7];
    const float* bl     = (const float*)d_in[8];
    const float* conv_w = (const float*)d_in[9];
    const float* conv_b = (const float*)d_in[10];
    const float* We     = (const float*)d_in[11];
    const float* be     = (const float*)d_in[12];
    const float* v_a    = (const float*)d_in[13];
    float* out = (float*)d_out;

    // workspace layout (float offsets)
    float* ws      = (float*)d_ws;
    float* zA      = ws;                  // 64*512 = 32768
    float* zS      = ws + 32768;          // 32768
    float* zSsum   = ws + 65536;          // 64
    float* zStsum  = ws + 65600;          // 64
    float* g_      = ws + 65664;          // 64*256 = 16384 (atomic-accumulated)
    float* zconst  = ws + 82048;          // 16384 (atomic-accumulated)
    float* WlWe    = ws + 98432;          // 32*256 = 8192
    ushort_t* WmWeT = (ushort_t*)(ws + 106624);           // 256*512 bf16
    ushort_t* CWT   = (ushort_t*)(ws + 106624 + 65536);   // 256*32 bf16
    // total ~705 KB

    // zero the atomic-accumulated regions [zA .. zconst): 98432 floats
    hipMemsetAsync(ws, 0, 98432 * sizeof(float), stream);
    hipMemsetAsync(out, 0, (size_t)Bq * Un * sizeof(float), stream);

    hipLaunchKernelGGL(k_wlwe,  dim3(FILTn),     dim3(Un), 0, stream, Wl, We, WlWe);
    hipLaunchKernelGGL(k_wmwet, dim3(ENCn),      dim3(Un), 0, stream, Wm, We, WmWeT);
    hipLaunchKernelGGL(k_g,     dim3(Bq, 8),     dim3(Un), 0, stream,
                       query, Wq, bq, bm, bl, Wl, conv_b, g_);
    hipLaunchKernelGGL(k_cwt,   dim3(32),        dim3(Un), 0, stream, conv_w, WlWe, CWT);
    hipLaunchKernelGGL(k_zconst,dim3(Bq, 4),     dim3(Un), 0, stream, g_, We, be, zconst);
    hipLaunchKernelGGL(attn_main, dim3(Bq * NCHUNK), dim3(256), 0, stream,
                       memory, state, WmWeT, CWT, zconst, v_a, zA, zS, zSsum, zStsum);
    hipLaunchKernelGGL(k_final, dim3(Bq, 4),     dim3(Un), 0, stream,
                       zA, zS, zSsum, zStsum, Wm, bm, out);
}